// Round 1
// 726.820 us; speedup vs baseline: 1.5974x; 1.5974x over previous
//
#include <hip/hip_runtime.h>
#include <math.h>

#define NB 16
#define CC 576
#define HH 12
#define WW 20
#define PP 240
#define MM 3840
#define NHEAD 8
#define HALO 22

typedef __attribute__((ext_vector_type(8))) short short8;
typedef __attribute__((ext_vector_type(4))) float floatx4;
typedef unsigned short ushort_t;

__device__ __forceinline__ float sigmoidf_(float x) {
    return 1.0f / (1.0f + expf(-x));
}
__device__ __forceinline__ unsigned short f2bf(float x) {
    union { float f; unsigned u; } v; v.f = x;
    unsigned r = v.u + 0x7fff + ((v.u >> 16) & 1);
    return (unsigned short)(r >> 16);
}
__device__ __forceinline__ float bf2f(unsigned short b) {
    union { float f; unsigned u; } v; v.u = ((unsigned)b) << 16;
    return v.f;
}

// ---------------- Kernel A: linear head + single_out (reads precomputed sums)
__global__ __launch_bounds__(256) void k_single(const float* __restrict__ f1sum,
                                                const float* __restrict__ linW,
                                                const float* __restrict__ linb,
                                                float* __restrict__ out) {
    int n = blockIdx.x;
    __shared__ float lin[10];
    int t = threadIdx.x;
    int lane = t & 63, wave = t >> 6;
    const float inv = 1.0f / PP;
    for (int o = wave; o < 10; o += 4) {
        const float* wrow = linW + o * CC;
        float s = 0.f;
        for (int c = lane; c < CC; c += 64)
            s = fmaf(f1sum[n * CC + c] * inv, wrow[c], s);
        #pragma unroll
        for (int off = 32; off; off >>= 1) s += __shfl_xor(s, off, 64);
        if (lane == 0) lin[o] = s + linb[o];
    }
    __syncthreads();
    if (t == 0) {
        const float eps = 1e-5f;
        float conf = sigmoidf_(lin[0]);
        conf = fminf(fmaxf(conf, eps), 1.f - eps);
        int best = 0; float bv = lin[1];
        #pragma unroll
        for (int j = 1; j < 5; ++j) { if (lin[1 + j] > bv) { bv = lin[1 + j]; best = j; } }
        float dist = 3.f * sigmoidf_(lin[6]);
        float offs = tanhf(lin[7]);
        float sev  = fminf(fmaxf(sigmoidf_(lin[8]), eps), 1.f - eps);
        float surf = fminf(fmaxf(sigmoidf_(lin[9]), eps), 1.f - eps);
        float* o = out + n * 6;
        o[0] = conf; o[1] = (float)best; o[2] = dist;
        o[3] = offs; o[4] = sev; o[5] = surf;
    }
}

// ---------------- prep: f[n][c][p] -> ft_hi/ft_lo [m][c] bf16, + channel sums
__global__ __launch_bounds__(256) void k_prep_f(const float* __restrict__ f,
                                                ushort_t* __restrict__ fhi,
                                                ushort_t* __restrict__ flo,
                                                float* __restrict__ f1sum) {
    __shared__ float tile[32][33];
    int c0 = blockIdx.x * 32, p0 = blockIdx.y * 32, n = blockIdx.z;
    int tp = threadIdx.x & 31, tc8 = threadIdx.x >> 5;
    for (int cc = tc8; cc < 32; cc += 8) {
        int p = p0 + tp;
        tile[cc][tp] = (p < PP) ? f[((size_t)n * CC + c0 + cc) * PP + p] : 0.f;
    }
    __syncthreads();
    // per-channel partial sums (tile is zero-padded past PP)
    if (threadIdx.x < 32) {
        float s = 0.f;
        #pragma unroll
        for (int pp = 0; pp < 32; ++pp) s += tile[threadIdx.x][pp];
        atomicAdd(&f1sum[n * CC + c0 + threadIdx.x], s);
    }
    int tcw = threadIdx.x & 31, tpw = threadIdx.x >> 5;
    for (int pp = tpw; pp < 32; pp += 8) {
        int p = p0 + pp;
        if (p < PP) {
            float v = tile[tcw][pp];
            unsigned short hi = f2bf(v);
            size_t o = ((size_t)n * PP + p) * CC + c0 + tcw;
            fhi[o] = hi;
            flo[o] = f2bf(v - bf2f(hi));
        }
    }
}

// ------ prep: w1[h][co][ci][tap] -> wt_hi/wt_lo [h][tap][co][ci] bf16 -----
// coalesced read into LDS, stride-9 LDS reads (9 coprime 32: conflict-free)
__global__ __launch_bounds__(256) void k_prep_w(const float* __restrict__ w1,
                                                ushort_t* __restrict__ whi,
                                                ushort_t* __restrict__ wlo) {
    __shared__ float ws[CC * 9];
    int co = blockIdx.x % CC;
    int h  = blockIdx.x / CC;
    const float* src = w1 + ((size_t)(h * CC + co)) * CC * 9;   // [ci][tap]
    for (int i = threadIdx.x; i < CC * 9; i += 256) ws[i] = src[i];
    __syncthreads();
    for (int tap = 0; tap < 9; ++tap) {
        size_t ob = ((size_t)(h * 9 + tap) * CC + co) * CC;
        for (int ci = threadIdx.x; ci < CC; ci += 256) {
            float v = ws[ci * 9 + tap];
            unsigned short hi = f2bf(v);
            whi[ob + ci] = hi;
            wlo[ob + ci] = f2bf(v - bf2f(hi));
        }
    }
}

// ---------------- init maps with bias + zero f1sum ------------------------
__global__ __launch_bounds__(256) void k_maps_init(float* __restrict__ maps,
                                                   const float* __restrict__ b2,
                                                   float* __restrict__ f1sum) {
    int i = blockIdx.x * 256 + threadIdx.x;
    if (i < NB * 14 * PP) {
        int o = (i / PP) % 14;
        maps[i] = b2[o];
    } else if (i < NB * 14 * PP + NB * CC) {
        f1sum[i - NB * 14 * PP] = 0.f;
    }
}

// ---------------- fused MFMA conv (bf16x3) + BN + SiLU + projection -------
// 1-D grid of 1080 blocks, XCD-swizzled: blockIdx.x = xcd + 8*(mt + 15*shi),
// so all 15 m-tiles of one (c0,h) weight slice run consecutively on ONE XCD
// (weight slice = 1.33 MB, fits its private L2). B staged via T14 reg
// prefetch: next tap's weights loaded to regs during current tap's MFMA.
__global__ __launch_bounds__(256) void k_conv_mfma(
        const ushort_t* __restrict__ fhi, const ushort_t* __restrict__ flo,
        const ushort_t* __restrict__ whi, const ushort_t* __restrict__ wlo,
        const float* __restrict__ w2,
        const float* __restrict__ bng, const float* __restrict__ bnb,
        const float* __restrict__ bnm, const float* __restrict__ bnv,
        float* __restrict__ maps) {
    // fragment-order LDS: chunk16(row,g) = (row>>4)*64 + g*16 + (row&15)
    __shared__ __align__(16) ushort_t Ah[1216 * 8];   // 304 rows x 32 k
    __shared__ __align__(16) ushort_t Al[1216 * 8];
    __shared__ __align__(16) ushort_t Bh[256 * 8];    // 64 co x 32 k
    __shared__ __align__(16) ushort_t Bl[256 * 8];
    __shared__ ushort_t rowmap[9 * 256];

    int t = threadIdx.x;

    // ---- XCD-aware swizzled block decode ----
    int bid = blockIdx.x;
    int xcd = bid & 7;
    int q = bid >> 3;              // 0..134
    int mt = q % 15;
    int slice = (q / 15) * 8 + xcd;  // 0..71, slice%8 == xcd
    int m0 = mt * 256;
    int c0 = (slice % 9) * 64;
    int h  = slice / 9;

    int w = t >> 6, lane = t & 63;
    int quad = lane >> 4, l15 = lane & 15;
    int srow_lo = t & 15, sg = (t >> 4) & 3, srb = t >> 6;

    // ---- prologue B prefetch (cib=0, tap=0) issued before LDS setup ----
    int bco = srb * 16 + srow_lo;
    size_t bconst = (size_t)(c0 + bco) * CC + sg * 8;
    const size_t hbase = (size_t)h * 9 * CC * CC;
    short8 pbh, pbl;
    {
        size_t src = hbase + bconst;
        pbh = *(const short8*)(whi + src);
        pbl = *(const short8*)(wlo + src);
    }

    // zero rows 300..303 (row-block 18, r&15 = 12..15) — never overwritten
    if (t < 32) {
        int arr = t >> 4, g = (t >> 2) & 3, rr = 12 + (t & 3);
        int idx = 18 * 64 + g * 16 + rr;
        short8 z = {0, 0, 0, 0, 0, 0, 0, 0};
        *(short8*)((arr ? Al : Ah) + idx * 8) = z;
    }
    // rowmap[tap][ml]: LDS A-row holding the tap-shifted source (300+x = zero)
    for (int idx = t; idx < 9 * 256; idx += 256) {
        int tap = idx >> 8, ml = idx & 255;
        int m = m0 + ml;
        int p = m % PP;
        int y = p / WW, x = p - y * WW;
        int dy = tap / 3 - 1, dx = tap % 3 - 1;
        int yy = y + dy, xx = x + dx;
        int row;
        if ((unsigned)yy < (unsigned)HH && (unsigned)xx < (unsigned)WW)
            row = ml + dy * WW + dx + HALO;
        else
            row = 300 + (ml & 3);
        rowmap[idx] = (ushort_t)row;
    }
    __syncthreads();

    floatx4 acc[4][4];
    #pragma unroll
    for (int i = 0; i < 4; ++i)
        #pragma unroll
        for (int j = 0; j < 4; ++j) acc[i][j] = (floatx4){0.f, 0.f, 0.f, 0.f};

    for (int cib = 0; cib < 18; ++cib) {
        __syncthreads();
        int koff = cib * 32 + sg * 8;
        // stage A hi/lo: 5 iters, lane-linear LDS chunk index = 256*it + t
        #pragma unroll
        for (int it = 0; it < 5; ++it) {
            int row = (srb + 4 * it) * 16 + srow_lo;
            if (row < 300) {
                int mg = m0 - HALO + row;
                int cidx = 256 * it + t;
                short8 vh = {0, 0, 0, 0, 0, 0, 0, 0};
                short8 vl = {0, 0, 0, 0, 0, 0, 0, 0};
                if ((unsigned)mg < (unsigned)MM) {
                    vh = *(const short8*)(fhi + (size_t)mg * CC + koff);
                    vl = *(const short8*)(flo + (size_t)mg * CC + koff);
                }
                *(short8*)(Ah + cidx * 8) = vh;
                *(short8*)(Al + cidx * 8) = vl;
            }
        }
        for (int tap = 0; tap < 9; ++tap) {
            if (tap) __syncthreads();
            // write the prefetched B fragment (loads issued one tap ago)
            *(short8*)(Bh + t * 8) = pbh;
            *(short8*)(Bl + t * 8) = pbl;
            // issue next tap's B loads — latency hides under this tap's MFMA
            int ntap = tap + 1, ncib = cib;
            if (ntap == 9) { ntap = 0; ncib = cib + 1; }
            if (ncib < 18) {
                size_t src = hbase + (size_t)ntap * (CC * CC) + bconst
                           + (size_t)ncib * 32;
                pbh = *(const short8*)(whi + src);
                pbl = *(const short8*)(wlo + src);
            }
            __syncthreads();

            short8 bh[4], bl[4], ah[4], al[4];
            #pragma unroll
            for (int j = 0; j < 4; ++j) {
                bh[j] = *(const short8*)(Bh + (j * 64 + lane) * 8);
                bl[j] = *(const short8*)(Bl + (j * 64 + lane) * 8);
            }
            #pragma unroll
            for (int i = 0; i < 4; ++i) {
                int r = rowmap[tap * 256 + w * 64 + i * 16 + l15];
                int a16 = ((r >> 4) * 64 + quad * 16 + (r & 15)) * 8;
                ah[i] = *(const short8*)(Ah + a16);
                al[i] = *(const short8*)(Al + a16);
            }
            #pragma unroll
            for (int i = 0; i < 4; ++i)
                #pragma unroll
                for (int j = 0; j < 4; ++j) {
                    acc[i][j] = __builtin_amdgcn_mfma_f32_16x16x32_bf16(
                        ah[i], bh[j], acc[i][j], 0, 0, 0);
                    acc[i][j] = __builtin_amdgcn_mfma_f32_16x16x32_bf16(
                        ah[i], bl[j], acc[i][j], 0, 0, 0);
                    acc[i][j] = __builtin_amdgcn_mfma_f32_16x16x32_bf16(
                        al[i], bh[j], acc[i][j], 0, 0, 0);
                }
        }
    }

    // ---- epilogue: BN + SiLU, then fused projection ----
    float scale[4], shift[4];
    #pragma unroll
    for (int j = 0; j < 4; ++j) {
        int c = h * CC + c0 + j * 16 + l15;
        float g_ = bng[c], bb = bnb[c], bm = bnm[c], bv = bnv[c];
        scale[j] = g_ / sqrtf(bv + 1e-5f);
        shift[j] = bb - bm * scale[j];
    }
    #pragma unroll
    for (int i = 0; i < 4; ++i)
        #pragma unroll
        for (int j = 0; j < 4; ++j)
            #pragma unroll
            for (int r = 0; r < 4; ++r) {
                float hx = fmaf(acc[i][j][r], scale[j], shift[j]);
                acc[i][j][r] = hx * sigmoidf_(hx);
            }

    static const int OFFo[NHEAD + 1] = {0, 5, 6, 8, 10, 11, 12, 13, 14};
    int o0 = OFFo[h], o1 = OFFo[h + 1];
    for (int o = o0; o < o1; ++o) {
        float w2v[4];
        #pragma unroll
        for (int j = 0; j < 4; ++j) w2v[j] = w2[o * CC + c0 + j * 16 + l15];
        float pv[4][4];
        #pragma unroll
        for (int i = 0; i < 4; ++i)
            #pragma unroll
            for (int r = 0; r < 4; ++r) {
                float s = 0.f;
                #pragma unroll
                for (int j = 0; j < 4; ++j) s = fmaf(acc[i][j][r], w2v[j], s);
                pv[i][r] = s;
            }
        #pragma unroll
        for (int off = 1; off < 16; off <<= 1)
            #pragma unroll
            for (int i = 0; i < 4; ++i)
                #pragma unroll
                for (int r = 0; r < 4; ++r)
                    pv[i][r] += __shfl_xor(pv[i][r], off, 64);
        if (l15 == 0) {
            #pragma unroll
            for (int i = 0; i < 4; ++i)
                #pragma unroll
                for (int r = 0; r < 4; ++r) {
                    int m = m0 + w * 64 + i * 16 + quad * 4 + r;
                    int n = m / PP, p = m - n * PP;
                    atomicAdd(&maps[(n * 14 + o) * PP + p], pv[i][r]);
                }
        }
    }
}

// ---------------- Kernel D: decode + top-k + distance sort ----------------
__global__ __launch_bounds__(256) void k_decode(
        const float* __restrict__ maps,
        const int* __restrict__ fw_p, const int* __restrict__ fh_p,
        float* __restrict__ out) {
    int n = blockIdx.x;
    int t = threadIdx.x;
    __shared__ float ms[14][PP];
    __shared__ float sconf[PP];
    __shared__ float cscore[100];
    __shared__ int   cidx[100];
    __shared__ float dets[100][10];
    __shared__ float dvals[100];

    const float* mp = maps + (size_t)n * 14 * PP;
    for (int idx = t; idx < 14 * PP; idx += 256) ms[idx / PP][idx % PP] = mp[idx];
    __syncthreads();
    if (t < PP) sconf[t] = sigmoidf_(ms[5][t]);
    __syncthreads();

    int wv = t >> 6, lane = t & 63;
    for (int cls = wv; cls < 5; cls += 4) {
        float v[4]; int pi[4];
        #pragma unroll
        for (int j = 0; j < 4; ++j) {
            int p = lane + 64 * j;
            pi[j] = p;
            v[j] = (p < PP) ? sconf[p] * sigmoidf_(ms[cls][p]) : -1e30f;
        }
        for (int r = 0; r < 20; ++r) {
            float bv = v[0]; int bi = pi[0];
            #pragma unroll
            for (int j = 1; j < 4; ++j)
                if (v[j] > bv || (v[j] == bv && pi[j] < bi)) { bv = v[j]; bi = pi[j]; }
            float rv = bv; int ri = bi;
            #pragma unroll
            for (int off = 32; off; off >>= 1) {
                float ov = __shfl_xor(rv, off, 64);
                int   oi = __shfl_xor(ri, off, 64);
                if (ov > rv || (ov == rv && oi < ri)) { rv = ov; ri = oi; }
            }
            if (lane == 0) { cscore[cls * 20 + r] = rv; cidx[cls * 20 + r] = ri; }
            #pragma unroll
            for (int j = 0; j < 4; ++j) if (pi[j] == ri) v[j] = -1e30f;
        }
    }
    __syncthreads();

    if (t < 100) {
        int cls = t / 20;
        int p = cidx[t];
        int yi = p / WW, xi = p - yi * WW;
        float gx = sigmoidf_(ms[6][p]),  gy = sigmoidf_(ms[7][p]);
        float gw = sigmoidf_(ms[8][p]),  gh = sigmoidf_(ms[9][p]);
        float gd = 3.f * sigmoidf_(ms[10][p]);
        float go = tanhf(ms[11][p]);
        float gs = sigmoidf_(ms[12][p]);
        float gf = sigmoidf_(ms[13][p]);
        float fw = (float)fw_p[0], fh = (float)fh_p[0];
        float sx = fw / (float)WW, sy = fh / (float)HH;
        float cx = fminf(fmaxf((float)xi + gx, 0.f), (float)WW - 1.f) * sx;
        float cy = fminf(fmaxf((float)yi + gy, 0.f), (float)HH - 1.f) * sy;
        float bw = fminf(fmaxf(gw, 0.f), 1.f) * fw;
        float bh = fminf(fmaxf(gh, 0.f), 1.f) * fh;
        float x1 = fminf(fmaxf(cx - bw * 0.5f, 0.f), fw - 1.f);
        float y1 = fminf(fmaxf(cy - bh * 0.5f, 0.f), fh - 1.f);
        float x2 = fminf(fmaxf(cx + bw * 0.5f, 0.f), fw - 1.f);
        float y2 = fminf(fmaxf(cy + bh * 0.5f, 0.f), fh - 1.f);
        dets[t][0] = cscore[t]; dets[t][1] = (float)cls;
        dets[t][2] = gd; dets[t][3] = go; dets[t][4] = gs; dets[t][5] = gf;
        dets[t][6] = x1; dets[t][7] = y1; dets[t][8] = x2; dets[t][9] = y2;
        dvals[t] = gd;
    }
    __syncthreads();
    if (t < 100) {
        float d = dvals[t];
        int rank = 0;
        for (int l = 0; l < 100; ++l) {
            float dl = dvals[l];
            rank += (dl < d) || (dl == d && l < t);
        }
        if (rank < 20) {
            float* o = out + 96 + ((size_t)n * 20 + rank) * 10;
            #pragma unroll
            for (int q = 0; q < 10; ++q) o[q] = dets[t][q];
        }
    }
}

extern "C" void kernel_launch(void* const* d_in, const int* in_sizes, int n_in,
                              void* d_out, int out_size, void* d_ws, size_t ws_size,
                              hipStream_t stream) {
    const float* f    = (const float*)d_in[0];
    const float* w1   = (const float*)d_in[1];
    const float* bng  = (const float*)d_in[2];
    const float* bnb  = (const float*)d_in[3];
    const float* bnm  = (const float*)d_in[4];
    const float* bnv  = (const float*)d_in[5];
    const float* w2   = (const float*)d_in[6];
    const float* b2   = (const float*)d_in[7];
    const float* linW = (const float*)d_in[8];
    const float* linb = (const float*)d_in[9];
    const int*   fw   = (const int*)d_in[10];
    const int*   fh   = (const int*)d_in[11];
    float* out = (float*)d_out;

    const size_t w_elems = (size_t)NHEAD * 9 * CC * CC;   // 23,887,872
    const size_t f_elems = (size_t)MM * CC;               //  2,211,840

    ushort_t* ws_whi = (ushort_t*)d_ws;
    ushort_t* ws_wlo = ws_whi + w_elems;
    ushort_t* ws_fhi = ws_wlo + w_elems;
    ushort_t* ws_flo = ws_fhi + f_elems;
    float*    ws_maps = (float*)(ws_flo + f_elems);
    // f1sum aliases the head of whi: it is dead before k_prep_w writes whi
    float*    ws_f1sum = (float*)d_ws;

    k_maps_init<<<(NB * 14 * PP + NB * CC + 255) / 256, 256, 0, stream>>>(
        ws_maps, b2, ws_f1sum);
    k_prep_f<<<dim3(CC / 32, (PP + 31) / 32, NB), 256, 0, stream>>>(
        f, ws_fhi, ws_flo, ws_f1sum);
    k_single<<<NB, 256, 0, stream>>>(ws_f1sum, linW, linb, out);
    k_prep_w<<<NHEAD * CC, 256, 0, stream>>>(w1, ws_whi, ws_wlo);
    k_conv_mfma<<<dim3(15 * 9 * NHEAD), 256, 0, stream>>>(
        ws_fhi, ws_flo, ws_whi, ws_wlo, w2, bng, bnb, bnm, bnv, ws_maps);
    k_decode<<<NB, 256, 0, stream>>>(ws_maps, fw, fh, out);
}